// Round 1
// 1311.579 us; speedup vs baseline: 1.1241x; 1.1241x over previous
//
#include <hip/hip_runtime.h>

typedef unsigned int  u32;
typedef unsigned short u16;

#define B_SESS 4096
#define NPS    40          // nodes / session
#define SPS    50          // seq tokens / session
#define EPS    60          // edges / session
#define DIM    512
#define HID    64
#define NNODES (B_SESS * NPS)

// ---------- bf16 helpers (RNE) ----------
__device__ __forceinline__ float bf2f(u32 b) { return __uint_as_float(b << 16); }
__device__ __forceinline__ u16  f2bf(float f) {
    u32 u = __float_as_uint(f);
    return (u16)((u + 0x7fffu + ((u >> 16) & 1u)) >> 16);
}
__device__ __forceinline__ u32 pack2(float a, float b) {
    return (u32)f2bf(a) | ((u32)f2bf(b) << 16);
}

typedef __bf16 bf16x8 __attribute__((ext_vector_type(8)));
typedef float  f32x4  __attribute__((ext_vector_type(4)));

typedef const __attribute__((address_space(1))) u32 gu32;
typedef       __attribute__((address_space(3))) u32 lu32;
#define GLOAD_LDS16(gp, lp) \
    __builtin_amdgcn_global_load_lds((gu32*)(gp), (lu32*)(lp), 16, 0, 0)

// ---------- transpose + fp32->bf16 convert: dst[c*R + r] = bf16(src[r*C + c]) ----
extern "C" __global__ void k_convT(const float* __restrict__ src,
                                   u16* __restrict__ dst, int R, int C) {
    int i = blockIdx.x * 256 + threadIdx.x;
    if (i < R * C) {
        int r = i / C, c = i % C;
        dst[c * R + r] = f2bf(src[i]);
    }
}

// ---------- SGConv 2-hop propagation: fp32 hidden -> bf16 xpr ----------
// one block per (session, 128-col chunk); X staged in LDS, both hops from LDS.
extern "C" __global__ __launch_bounds__(128)
void k_prop(const float* __restrict__ hid, const int* __restrict__ eidx, int Etot,
            u16* __restrict__ xpr) {
    __shared__ float X [NPS * 128];          // staged hidden chunk (20 KB)
    __shared__ float xl[NPS * 128];          // hop1 result (20 KB)
    __shared__ int   esrc[NPS + EPS];        // CSR entry source node
    __shared__ float enrm[NPS + EPS];        // CSR entry norm
    __shared__ int   degc[NPS];
    __shared__ int   offs[NPS + 1];
    __shared__ int   cur[NPS];
    __shared__ float dinv[NPS];
    __shared__ int   se[EPS], de[EPS];

    int tid  = threadIdx.x;
    int lane = tid & 63, w = tid >> 6;
    int b    = blockIdx.x >> 2;
    int c0   = (blockIdx.x & 3) * 128;
    size_t nb = (size_t)b * NPS;

    if (tid < EPS) {
        se[tid] = eidx[b * EPS + tid] - (int)nb;
        de[tid] = eidx[Etot + b * EPS + tid] - (int)nb;
    }

    // issue X staging early: 20 chunks of 1 KB (2 rows x 128 cols each),
    // wave-uniform LDS base, lane covers (row = 2q + lane/32, col = (lane%32)*4)
    for (int q = w; q < NPS / 2; q += 2) {
        int row = 2 * q + (lane >> 5);
        GLOAD_LDS16(hid + (nb + row) * DIM + c0 + (lane & 31) * 4, X + q * 256);
    }

    if (tid < NPS) degc[tid] = 1;            // self loop
    __syncthreads();                         // (also drains staging loads)
    if (tid < EPS) atomicAdd(&degc[de[tid]], 1);
    __syncthreads();
    if (tid == 0) {
        int s = 0;
        for (int i = 0; i < NPS; i++) { offs[i] = s; s += degc[i]; }
        offs[NPS] = s;                       // == NPS + EPS
    }
    if (tid < NPS) dinv[tid] = rsqrtf((float)degc[tid]);
    __syncthreads();
    if (tid < NPS) cur[tid] = offs[tid];
    __syncthreads();
    if (tid < NPS) {                         // self-loop entries
        int p = atomicAdd(&cur[tid], 1);
        esrc[p] = tid;
        enrm[p] = dinv[tid] * dinv[tid];
    }
    if (tid < EPS) {                         // real edges
        int s = se[tid], d = de[tid];
        int p = atomicAdd(&cur[d], 1);
        esrc[p] = s;
        enrm[p] = dinv[s] * dinv[d];
    }
    __syncthreads();

    // ---- hop 1: gather from LDS X, store fp32 to xl ----
    for (int d = 0; d < NPS; d++) {
        float a = 0.f;
        int pe = offs[d + 1];
        for (int p = offs[d]; p < pe; p++)
            a += enrm[p] * X[esrc[p] * 128 + tid];
        xl[d * 128 + tid] = a;
    }
    __syncthreads();

    // ---- hop 2: gather from xl, write bf16 xpr (coalesced stream) ----
    for (int d = 0; d < NPS; d++) {
        float a = 0.f;
        int pe = offs[d + 1];
        for (int p = offs[d]; p < pe; p++)
            a += enrm[p] * xl[esrc[p] * 128 + tid];
        xpr[(nb + d) * DIM + c0 + tid] = f2bf(a);
    }
}

// ---------- GEMM1: C[N,512] = A[N,512] @ Wg + bg (A,BT,C bf16; bias fp32) --------
// 1D grid, XCD-chunked swizzle; N-block varies fastest within an XCD chunk so the
// 4 blocks sharing an A panel are co-resident on one XCD (A read once from HBM).
#define GEMM_NBLK ((NNODES / 128) * (DIM / 128))   // 5120, % 8 == 0
extern "C" __global__ __launch_bounds__(256)
void k_gemm(const u16* __restrict__ A, const u16* __restrict__ BT,
            const float* __restrict__ bias, u16* __restrict__ C) {
    __shared__ __align__(16) u16 As[128 * 32];
    __shared__ __align__(16) u16 Bs[128 * 32];
    int tid  = threadIdx.x, lane = tid & 63, w = tid >> 6;
    int id   = blockIdx.x;
    int swz  = (id & 7) * (GEMM_NBLK / 8) + (id >> 3);
    int m0   = (swz >> 2) * 128, n0 = (swz & 3) * 128;
    int wm   = (w >> 1) * 64,    wn = (w & 1) * 64;
    int fr   = lane & 15,        kq = (lane >> 4) * 8;
    int lr   = lane >> 2;              // staging: row within 16-row chunk
    int lk   = (lane & 3) * 8;         // staging: k offset (u16 units)
    f32x4 acc[4][4] = {};

    for (int kt = 0; kt < 16; kt++) {
        __syncthreads();
        int k0 = kt * 32;
#pragma unroll
        for (int q = 0; q < 2; q++) {
            int r0 = (w * 2 + q) * 16;
            GLOAD_LDS16(A  + (size_t)(m0 + r0 + lr) * DIM + k0 + lk, As + r0 * 32);
            GLOAD_LDS16(BT + (size_t)(n0 + r0 + lr) * DIM + k0 + lk, Bs + r0 * 32);
        }
        __syncthreads();
        bf16x8 av[4], bv[4];
#pragma unroll
        for (int f = 0; f < 4; f++)
            av[f] = *(const bf16x8*)&As[(wm + f * 16 + fr) * 32 + kq];
#pragma unroll
        for (int f = 0; f < 4; f++)
            bv[f] = *(const bf16x8*)&Bs[(wn + f * 16 + fr) * 32 + kq];
#pragma unroll
        for (int fm = 0; fm < 4; fm++)
#pragma unroll
            for (int fn = 0; fn < 4; fn++)
                acc[fm][fn] = __builtin_amdgcn_mfma_f32_16x16x32_bf16(
                    av[fm], bv[fn], acc[fm][fn], 0, 0, 0);
    }

    float bs[4];
#pragma unroll
    for (int fn = 0; fn < 4; fn++) bs[fn] = bias[n0 + wn + fn * 16 + fr];
#pragma unroll
    for (int fm = 0; fm < 4; fm++) {
        int mb = m0 + wm + fm * 16 + (lane >> 4) * 4;
#pragma unroll
        for (int fn = 0; fn < 4; fn++) {
            int col = n0 + wn + fn * 16 + fr;
#pragma unroll
            for (int r = 0; r < 4; r++)
                C[(size_t)(mb + r) * DIM + col] = f2bf(acc[fm][fn][r] + bs[fn]);
        }
    }
}

// ---------- fused attention pooling, one block per session ----------
extern "C" __global__ __launch_bounds__(256)
void k_attn(const u16* __restrict__ xg, const float* __restrict__ W1,
            const float* __restrict__ b1, const float* __restrict__ b2,
            const u16* __restrict__ W2T, const float* __restrict__ Wq,
            const float* __restrict__ bq, const float* __restrict__ W3,
            const float* __restrict__ b3, const int* __restrict__ sidx,
            float* __restrict__ out) {
    __shared__ __align__(16) u16 th[64 * 520];   // tokens x D bf16, stride 520
    __shared__ float q1s[64], wqs[64], alphas[64], sgs[512], part[256];
    int tid = threadIdx.x, lane = tid & 63, w = tid >> 6;
    int b = blockIdx.x, sb = b * SPS;
    size_t nb = (size_t)b * NPS;

    // gather token rows (1 KB each == one global_load_lds_dwordx4 per wave)
    for (int t = w; t < SPS; t += 4) {
        size_t g = nb + sidx[sb + t];
        GLOAD_LDS16(xg + g * DIM + lane * 8, th + t * 520);
    }
    // zero pad rows 50..63 (MFMA reads them)
    for (int i = tid; i < 14 * 260; i += 256) {
        int r = i / 260, c = i % 260;
        *(u32*)&th[(50 + r) * 520 + c * 2] = 0;
    }
    if (tid < 64) wqs[tid] = Wq[tid];
    __syncthreads();

    // q1[j] = v_n @ W1 + b1 + b2   (v_n = th[49]); wave w covers a 128-k chunk
    {
        float s = 0.f;
        for (int k = 128 * w; k < 128 * w + 128; k++)
            s += bf2f(th[49 * 520 + k]) * W1[k * HID + lane];
        part[w * 64 + lane] = s;
    }
    __syncthreads();
    if (tid < 64)
        q1s[tid] = part[tid] + part[64 + tid] + part[128 + tid] + part[192 + tid]
                 + b1[tid] + b2[tid];
    __syncthreads();

    // a2 = tok_h @ W2 via MFMA; wave w owns tokens 16w..16w+15
    int fr = lane & 15, kq = (lane >> 4) * 8;
    f32x4 acc[4] = {};
    for (int kt = 0; kt < 16; kt++) {
        bf16x8 av = *(const bf16x8*)&th[(w * 16 + fr) * 520 + kt * 32 + kq];
#pragma unroll
        for (int fn = 0; fn < 4; fn++) {
            bf16x8 bv = *(const bf16x8*)&W2T[(size_t)(fn * 16 + fr) * DIM + kt * 32 + kq];
            acc[fn] = __builtin_amdgcn_mfma_f32_16x16x32_bf16(av, bv, acc[fn], 0, 0, 0);
        }
    }
    // alpha[t] = sigmoid(a2 + q1) . wq + bq  (reduce across 16-lane groups)
    float bqf = bq[0];
#pragma unroll
    for (int r = 0; r < 4; r++) {
        float s = 0.f;
#pragma unroll
        for (int fn = 0; fn < 4; fn++) {
            int j = fn * 16 + fr;
            float x = acc[fn][r] + q1s[j];
            float sg = 1.0f / (1.0f + __expf(-x));
            s += sg * wqs[j];
        }
        s += __shfl_xor(s, 1); s += __shfl_xor(s, 2);
        s += __shfl_xor(s, 4); s += __shfl_xor(s, 8);
        if (fr == 0) alphas[w * 16 + (lane >> 4) * 4 + r] = s + bqf;
    }
    __syncthreads();

    // s_g[d] = sum_t alpha[t] * tok_h[t][d]
    {
        float a0 = 0.f, a1 = 0.f;
        int d = tid * 2;
        for (int t = 0; t < SPS; t++) {
            float al = alphas[t];
            u32 xv = *(const u32*)&th[t * 520 + d];
            a0 += al * bf2f(xv & 0xffffu);
            a1 += al * bf2f(xv >> 16);
        }
        sgs[d] = a0; sgs[d + 1] = a1;
    }
    __syncthreads();

    // h_s = [v_n, s_g] @ W3 + b3   (W3 fp32)
    {
        float s = 0.f;
        for (int k = 256 * w; k < 256 * w + 256; k++) {
            float v = (k < DIM) ? bf2f(th[49 * 520 + k]) : sgs[k - DIM];
            s += v * W3[k * HID + lane];
        }
        part[w * 64 + lane] = s;
    }
    __syncthreads();
    if (tid < 64) {
        out[b * HID + tid] = part[tid] + part[64 + tid] + part[128 + tid]
                           + part[192 + tid] + b3[tid];
    }
}

extern "C" void kernel_launch(void* const* d_in, const int* in_sizes, int n_in,
                              void* d_out, int out_size, void* d_ws, size_t ws_size,
                              hipStream_t stream) {
    const float* hidden = (const float*)d_in[0];
    const float* Wg     = (const float*)d_in[1];
    const float* bg     = (const float*)d_in[2];
    const float* W1     = (const float*)d_in[3];
    const float* b1     = (const float*)d_in[4];
    const float* W2     = (const float*)d_in[5];
    const float* b2     = (const float*)d_in[6];
    const float* Wq     = (const float*)d_in[7];
    const float* bq     = (const float*)d_in[8];
    const float* W3     = (const float*)d_in[9];
    const float* b3     = (const float*)d_in[10];
    const int*   eidx   = (const int*)d_in[11];
    const int*   sidx   = (const int*)d_in[13];
    int Etot = in_sizes[11] / 2;

    char* ws = (char*)d_ws;
    u16* xpr = (u16*)ws;                                   // N*D bf16 (160 MB)
    u16* xg  = (u16*)(ws + (size_t)NNODES * DIM * 2);      // N*D bf16 (160 MB)
    u16* WgT = (u16*)(ws + (size_t)NNODES * DIM * 4);      // 512x512 bf16
    u16* W2T = WgT + DIM * DIM;                            // 64x512  bf16

    k_convT<<<dim3((DIM * DIM + 255) / 256), 256, 0, stream>>>(Wg, WgT, DIM, DIM);
    k_convT<<<dim3((DIM * HID + 255) / 256), 256, 0, stream>>>(W2, W2T, DIM, HID);
    k_prop<<<dim3(B_SESS * 4), 128, 0, stream>>>(hidden, eidx, Etot, xpr);
    k_gemm<<<dim3(GEMM_NBLK), 256, 0, stream>>>(xpr, WgT, bg, xg);
    k_attn<<<dim3(B_SESS), 256, 0, stream>>>(xg, W1, b1, b2, W2T, Wq, bq, W3, b3,
                                             sidx, (float*)d_out);
}

// Round 2
// 1181.862 us; speedup vs baseline: 1.2474x; 1.1098x over previous
//
#include <hip/hip_runtime.h>

typedef unsigned int  u32;
typedef unsigned short u16;

#define B_SESS 4096
#define NPS    40          // nodes / session
#define SPS    50          // seq tokens / session
#define EPS    60          // edges / session
#define NENT   (NPS + EPS) // CSR entries / session (always exactly 100)
#define DIM    512
#define HID    64
#define NNODES (B_SESS * NPS)

// ---------- bf16 helpers (RNE) ----------
__device__ __forceinline__ float bf2f(u32 b) { return __uint_as_float(b << 16); }
__device__ __forceinline__ u16  f2bf(float f) {
    u32 u = __float_as_uint(f);
    return (u16)((u + 0x7fffu + ((u >> 16) & 1u)) >> 16);
}

typedef __bf16 bf16x8 __attribute__((ext_vector_type(8)));
typedef float  f32x4  __attribute__((ext_vector_type(4)));

typedef const __attribute__((address_space(1))) u32 gu32;
typedef       __attribute__((address_space(3))) u32 lu32;
#define GLOAD_LDS16(gp, lp) \
    __builtin_amdgcn_global_load_lds((gu32*)(gp), (lu32*)(lp), 16, 0, 0)

// ---------- transpose + fp32->bf16 convert: dst[c*R + r] = bf16(src[r*C + c]) ----
extern "C" __global__ void k_convT(const float* __restrict__ src,
                                   u16* __restrict__ dst, int R, int C) {
    int i = blockIdx.x * 256 + threadIdx.x;
    if (i < R * C) {
        int r = i / C, c = i % C;
        dst[c * R + r] = f2bf(src[i]);
    }
}

// ---------- CSR build, one block per session ----------
// Emits a flat dst-sorted entry stream per session (stride 128 entries):
//   e.x = (isLastOfDst << 16) | (dst << 8) | src,  e.y = bits(norm)
extern "C" __global__ __launch_bounds__(128)
void k_csr(const int* __restrict__ eidx, int Etot, uint2* __restrict__ cs) {
    __shared__ int   degc[NPS];
    __shared__ int   offs[NPS + 1];
    __shared__ int   cur[NPS];
    __shared__ float dinv[NPS];
    __shared__ int   se[EPS], de[EPS];
    __shared__ u32   eid[NENT + 1];
    __shared__ float enm[NENT];

    int tid = threadIdx.x;
    int b   = blockIdx.x;
    int nb  = b * NPS;

    if (tid < EPS) {
        se[tid] = eidx[b * EPS + tid] - nb;
        de[tid] = eidx[Etot + b * EPS + tid] - nb;
    }
    if (tid < NPS) degc[tid] = 1;            // self loop
    __syncthreads();
    if (tid < EPS) atomicAdd(&degc[de[tid]], 1);
    __syncthreads();
    if (tid == 0) {
        int s = 0;
        for (int i = 0; i < NPS; i++) { offs[i] = s; s += degc[i]; }
        offs[NPS] = s;                       // == NENT
    }
    if (tid < NPS) dinv[tid] = rsqrtf((float)degc[tid]);
    __syncthreads();
    if (tid < NPS) cur[tid] = offs[tid];
    __syncthreads();
    if (tid < NPS) {                         // self-loop entries
        int p = atomicAdd(&cur[tid], 1);
        eid[p] = (u32)(tid << 8) | (u32)tid;
        enm[p] = dinv[tid] * dinv[tid];
    }
    if (tid < EPS) {                         // real edges
        int s = se[tid], d = de[tid];
        int p = atomicAdd(&cur[d], 1);
        eid[p] = (u32)(d << 8) | (u32)s;
        enm[p] = dinv[s] * dinv[d];
    }
    __syncthreads();
    if (tid < NENT) {
        u32 id = eid[tid];
        u32 last = (tid == NENT - 1) ? 1u : (u32)((eid[tid + 1] >> 8) != (id >> 8));
        cs[(size_t)b * 128 + tid] = make_uint2(id | (last << 16), __float_as_uint(enm[tid]));
    }
}

// ---------- SGConv 2-hop propagation: fp32 hidden -> bf16 xpr ----------
// one block per (session, 128-col chunk). Flat branch-free entry loop, static
// trip count 100; hop1 gathers from global (L2-resident), xl is the only big
// LDS buffer (21 KB total -> 7 blocks/CU). xl accesses are column-local, so no
// barrier is needed between the hops.
extern "C" __global__ __launch_bounds__(128)
void k_prop(const float* __restrict__ hid, const uint2* __restrict__ cs,
            u16* __restrict__ xpr) {
    __shared__ float xl[NPS * 128];          // hop1 result (20 KB)
    __shared__ uint2 em[NENT];               // packed entries (800 B)

    int tid = threadIdx.x;
    int b   = blockIdx.x >> 2;
    int c0  = (blockIdx.x & 3) * 128;
    size_t nb = (size_t)b * NPS;

    if (tid < NENT) em[tid] = cs[(size_t)b * 128 + tid];
    __syncthreads();

    const float* __restrict__ xcol = hid + nb * DIM + c0 + tid;

    // ---- hop 1: gather from global (L2), accumulate, last-write-wins to xl ----
    {
        float a = 0.f; int prev = -1;
#pragma unroll 4
        for (int p = 0; p < NENT; p++) {
            uint2 e = em[p];
            int d = (e.x >> 8) & 0xff, s = e.x & 0xff;
            float nm = __uint_as_float(e.y);
            float xv = xcol[(size_t)s * DIM];
            a = (d == prev ? a : 0.f) + nm * xv;
            xl[d * 128 + tid] = a;           // unconditional; final write is full sum
            prev = d;
        }
    }

    // ---- hop 2: gather from xl (same-thread columns), write bf16 xpr ----
    {
        float a = 0.f; int prev = -1;
#pragma unroll 4
        for (int p = 0; p < NENT; p++) {
            uint2 e = em[p];
            int d = (e.x >> 8) & 0xff, s = e.x & 0xff;
            float nm = __uint_as_float(e.y);
            float xv = xl[s * 128 + tid];
            a = (d == prev ? a : 0.f) + nm * xv;
            prev = d;
            if (e.x & 0x10000u)
                xpr[(nb + d) * DIM + c0 + tid] = f2bf(a);
        }
    }
}

// ---------- GEMM1: C[N,512] = A[N,512] @ Wg + bg (A,BT,C bf16; bias fp32) --------
// 1D grid, XCD-chunked swizzle; N-block varies fastest within an XCD chunk so the
// 4 blocks sharing an A panel are co-resident on one XCD (A read once from HBM).
#define GEMM_NBLK ((NNODES / 128) * (DIM / 128))   // 5120, % 8 == 0
extern "C" __global__ __launch_bounds__(256)
void k_gemm(const u16* __restrict__ A, const u16* __restrict__ BT,
            const float* __restrict__ bias, u16* __restrict__ C) {
    __shared__ __align__(16) u16 As[128 * 32];
    __shared__ __align__(16) u16 Bs[128 * 32];
    int tid  = threadIdx.x, lane = tid & 63, w = tid >> 6;
    int id   = blockIdx.x;
    int swz  = (id & 7) * (GEMM_NBLK / 8) + (id >> 3);
    int m0   = (swz >> 2) * 128, n0 = (swz & 3) * 128;
    int wm   = (w >> 1) * 64,    wn = (w & 1) * 64;
    int fr   = lane & 15,        kq = (lane >> 4) * 8;
    int lr   = lane >> 2;              // staging: row within 16-row chunk
    int lk   = (lane & 3) * 8;         // staging: k offset (u16 units)
    f32x4 acc[4][4] = {};

    for (int kt = 0; kt < 16; kt++) {
        __syncthreads();
        int k0 = kt * 32;
#pragma unroll
        for (int q = 0; q < 2; q++) {
            int r0 = (w * 2 + q) * 16;
            GLOAD_LDS16(A  + (size_t)(m0 + r0 + lr) * DIM + k0 + lk, As + r0 * 32);
            GLOAD_LDS16(BT + (size_t)(n0 + r0 + lr) * DIM + k0 + lk, Bs + r0 * 32);
        }
        __syncthreads();
        bf16x8 av[4], bv[4];
#pragma unroll
        for (int f = 0; f < 4; f++)
            av[f] = *(const bf16x8*)&As[(wm + f * 16 + fr) * 32 + kq];
#pragma unroll
        for (int f = 0; f < 4; f++)
            bv[f] = *(const bf16x8*)&Bs[(wn + f * 16 + fr) * 32 + kq];
#pragma unroll
        for (int fm = 0; fm < 4; fm++)
#pragma unroll
            for (int fn = 0; fn < 4; fn++)
                acc[fm][fn] = __builtin_amdgcn_mfma_f32_16x16x32_bf16(
                    av[fm], bv[fn], acc[fm][fn], 0, 0, 0);
    }

    float bs[4];
#pragma unroll
    for (int fn = 0; fn < 4; fn++) bs[fn] = bias[n0 + wn + fn * 16 + fr];
#pragma unroll
    for (int fm = 0; fm < 4; fm++) {
        int mb = m0 + wm + fm * 16 + (lane >> 4) * 4;
#pragma unroll
        for (int fn = 0; fn < 4; fn++) {
            int col = n0 + wn + fn * 16 + fr;
#pragma unroll
            for (int r = 0; r < 4; r++)
                C[(size_t)(mb + r) * DIM + col] = f2bf(acc[fm][fn][r] + bs[fn]);
        }
    }
}

// ---------- fused attention pooling, one block per session ----------
extern "C" __global__ __launch_bounds__(256)
void k_attn(const u16* __restrict__ xg, const float* __restrict__ W1,
            const float* __restrict__ b1, const float* __restrict__ b2,
            const u16* __restrict__ W2T, const float* __restrict__ Wq,
            const float* __restrict__ bq, const float* __restrict__ W3,
            const float* __restrict__ b3, const int* __restrict__ sidx,
            float* __restrict__ out) {
    __shared__ __align__(16) u16 th[64 * 520];   // tokens x D bf16, stride 520
    __shared__ float q1s[64], wqs[64], alphas[64], sgs[512], part[256];
    int tid = threadIdx.x, lane = tid & 63, w = tid >> 6;
    int b = blockIdx.x, sb = b * SPS;
    size_t nb = (size_t)b * NPS;

    // gather token rows (1 KB each == one global_load_lds_dwordx4 per wave)
    for (int t = w; t < SPS; t += 4) {
        size_t g = nb + sidx[sb + t];
        GLOAD_LDS16(xg + g * DIM + lane * 8, th + t * 520);
    }
    // zero pad rows 50..63 (MFMA reads them)
    for (int i = tid; i < 14 * 260; i += 256) {
        int r = i / 260, c = i % 260;
        *(u32*)&th[(50 + r) * 520 + c * 2] = 0;
    }
    if (tid < 64) wqs[tid] = Wq[tid];
    __syncthreads();

    // q1[j] = v_n @ W1 + b1 + b2   (v_n = th[49]); wave w covers a 128-k chunk
    {
        float s = 0.f;
        for (int k = 128 * w; k < 128 * w + 128; k++)
            s += bf2f(th[49 * 520 + k]) * W1[k * HID + lane];
        part[w * 64 + lane] = s;
    }
    __syncthreads();
    if (tid < 64)
        q1s[tid] = part[tid] + part[64 + tid] + part[128 + tid] + part[192 + tid]
                 + b1[tid] + b2[tid];
    __syncthreads();

    // a2 = tok_h @ W2 via MFMA; wave w owns tokens 16w..16w+15
    int fr = lane & 15, kq = (lane >> 4) * 8;
    f32x4 acc[4] = {};
    for (int kt = 0; kt < 16; kt++) {
        bf16x8 av = *(const bf16x8*)&th[(w * 16 + fr) * 520 + kt * 32 + kq];
#pragma unroll
        for (int fn = 0; fn < 4; fn++) {
            bf16x8 bv = *(const bf16x8*)&W2T[(size_t)(fn * 16 + fr) * DIM + kt * 32 + kq];
            acc[fn] = __builtin_amdgcn_mfma_f32_16x16x32_bf16(av, bv, acc[fn], 0, 0, 0);
        }
    }
    // alpha[t] = sigmoid(a2 + q1) . wq + bq  (reduce across 16-lane groups)
    float bqf = bq[0];
#pragma unroll
    for (int r = 0; r < 4; r++) {
        float s = 0.f;
#pragma unroll
        for (int fn = 0; fn < 4; fn++) {
            int j = fn * 16 + fr;
            float x = acc[fn][r] + q1s[j];
            float sg = 1.0f / (1.0f + __expf(-x));
            s += sg * wqs[j];
        }
        s += __shfl_xor(s, 1); s += __shfl_xor(s, 2);
        s += __shfl_xor(s, 4); s += __shfl_xor(s, 8);
        if (fr == 0) alphas[w * 16 + (lane >> 4) * 4 + r] = s + bqf;
    }
    __syncthreads();

    // s_g[d] = sum_t alpha[t] * tok_h[t][d]
    {
        float a0 = 0.f, a1 = 0.f;
        int d = tid * 2;
        for (int t = 0; t < SPS; t++) {
            float al = alphas[t];
            u32 xv = *(const u32*)&th[t * 520 + d];
            a0 += al * bf2f(xv & 0xffffu);
            a1 += al * bf2f(xv >> 16);
        }
        sgs[d] = a0; sgs[d + 1] = a1;
    }
    __syncthreads();

    // h_s = [v_n, s_g] @ W3 + b3   (W3 fp32)
    {
        float s = 0.f;
        for (int k = 256 * w; k < 256 * w + 256; k++) {
            float v = (k < DIM) ? bf2f(th[49 * 520 + k]) : sgs[k - DIM];
            s += v * W3[k * HID + lane];
        }
        part[w * 64 + lane] = s;
    }
    __syncthreads();
    if (tid < 64) {
        out[b * HID + tid] = part[tid] + part[64 + tid] + part[128 + tid]
                           + part[192 + tid] + b3[tid];
    }
}

extern "C" void kernel_launch(void* const* d_in, const int* in_sizes, int n_in,
                              void* d_out, int out_size, void* d_ws, size_t ws_size,
                              hipStream_t stream) {
    const float* hidden = (const float*)d_in[0];
    const float* Wg     = (const float*)d_in[1];
    const float* bg     = (const float*)d_in[2];
    const float* W1     = (const float*)d_in[3];
    const float* b1     = (const float*)d_in[4];
    const float* W2     = (const float*)d_in[5];
    const float* b2     = (const float*)d_in[6];
    const float* Wq     = (const float*)d_in[7];
    const float* bq     = (const float*)d_in[8];
    const float* W3     = (const float*)d_in[9];
    const float* b3     = (const float*)d_in[10];
    const int*   eidx   = (const int*)d_in[11];
    const int*   sidx   = (const int*)d_in[13];
    int Etot = in_sizes[11] / 2;

    char* ws = (char*)d_ws;
    u16* xpr = (u16*)ws;                                   // N*D bf16 (160 MB)
    u16* xg  = (u16*)(ws + (size_t)NNODES * DIM * 2);      // N*D bf16 (160 MB)
    u16* WgT = (u16*)(ws + (size_t)NNODES * DIM * 4);      // 512x512 bf16
    u16* W2T = WgT + DIM * DIM;                            // 64x512  bf16
    uint2* cs = (uint2*)(W2T + DIM * HID);                 // 4096x128 uint2 (4 MB)

    k_convT<<<dim3((DIM * DIM + 255) / 256), 256, 0, stream>>>(Wg, WgT, DIM, DIM);
    k_convT<<<dim3((DIM * HID + 255) / 256), 256, 0, stream>>>(W2, W2T, DIM, HID);
    k_csr<<<dim3(B_SESS), 128, 0, stream>>>(eidx, Etot, cs);
    k_prop<<<dim3(B_SESS * 4), 128, 0, stream>>>(hidden, cs, xpr);
    k_gemm<<<dim3(GEMM_NBLK), 256, 0, stream>>>(xpr, WgT, bg, xg);
    k_attn<<<dim3(B_SESS), 256, 0, stream>>>(xg, W1, b1, b2, W2T, Wq, bq, W3, b3,
                                             sidx, (float*)d_out);
}

// Round 3
// 975.500 us; speedup vs baseline: 1.5113x; 1.2115x over previous
//
#include <hip/hip_runtime.h>

typedef unsigned int  u32;
typedef unsigned short u16;

#define B_SESS 4096
#define NPS    40          // nodes / session
#define SPS    50          // seq tokens / session
#define EPS    60          // edges / session
#define NENT   (NPS + EPS) // CSR entries / session (always exactly 100)
#define DIM    512
#define HID    64
#define NNODES (B_SESS * NPS)

// ---------- bf16 helpers (RNE) ----------
__device__ __forceinline__ float bf2f(u32 b) { return __uint_as_float(b << 16); }
__device__ __forceinline__ u16  f2bf(float f) {
    u32 u = __float_as_uint(f);
    return (u16)((u + 0x7fffu + ((u >> 16) & 1u)) >> 16);
}

typedef __bf16 bf16x8 __attribute__((ext_vector_type(8)));
typedef float  f32x4  __attribute__((ext_vector_type(4)));

typedef const __attribute__((address_space(1))) u32 gu32;
typedef       __attribute__((address_space(3))) u32 lu32;
#define GLOAD_LDS16(gp, lp) \
    __builtin_amdgcn_global_load_lds((gu32*)(gp), (lu32*)(lp), 16, 0, 0)

// ---------- transpose + fp32->bf16 convert: dst[c*R + r] = bf16(src[r*C + c]) ----
extern "C" __global__ void k_convT(const float* __restrict__ src,
                                   u16* __restrict__ dst, int R, int C) {
    int i = blockIdx.x * 256 + threadIdx.x;
    if (i < R * C) {
        int r = i / C, c = i % C;
        dst[c * R + r] = f2bf(src[i]);
    }
}

// ---------- CSR build, one block per session ----------
// Emits a flat dst-sorted entry stream per session (stride 128 entries):
//   e.x = (isLastOfDst << 16) | (dst << 8) | src,  e.y = bits(norm)
extern "C" __global__ __launch_bounds__(128)
void k_csr(const int* __restrict__ eidx, int Etot, uint2* __restrict__ cs) {
    __shared__ int   degc[NPS];
    __shared__ int   offs[NPS + 1];
    __shared__ int   cur[NPS];
    __shared__ float dinv[NPS];
    __shared__ int   se[EPS], de[EPS];
    __shared__ u32   eid[NENT + 1];
    __shared__ float enm[NENT];

    int tid = threadIdx.x;
    int b   = blockIdx.x;
    int nb  = b * NPS;

    if (tid < EPS) {
        se[tid] = eidx[b * EPS + tid] - nb;
        de[tid] = eidx[Etot + b * EPS + tid] - nb;
    }
    if (tid < NPS) degc[tid] = 1;            // self loop
    __syncthreads();
    if (tid < EPS) atomicAdd(&degc[de[tid]], 1);
    __syncthreads();
    if (tid == 0) {
        int s = 0;
        for (int i = 0; i < NPS; i++) { offs[i] = s; s += degc[i]; }
        offs[NPS] = s;                       // == NENT
    }
    if (tid < NPS) dinv[tid] = rsqrtf((float)degc[tid]);
    __syncthreads();
    if (tid < NPS) cur[tid] = offs[tid];
    __syncthreads();
    if (tid < NPS) {                         // self-loop entries
        int p = atomicAdd(&cur[tid], 1);
        eid[p] = (u32)(tid << 8) | (u32)tid;
        enm[p] = dinv[tid] * dinv[tid];
    }
    if (tid < EPS) {                         // real edges
        int s = se[tid], d = de[tid];
        int p = atomicAdd(&cur[d], 1);
        eid[p] = (u32)(d << 8) | (u32)s;
        enm[p] = dinv[s] * dinv[d];
    }
    __syncthreads();
    if (tid < NENT) {
        u32 id = eid[tid];
        u32 last = (tid == NENT - 1) ? 1u : (u32)((eid[tid + 1] >> 8) != (id >> 8));
        cs[(size_t)b * 128 + tid] = make_uint2(id | (last << 16), __float_as_uint(enm[tid]));
    }
}

// ---------- SGConv 2-hop propagation: fp32 hidden -> bf16 xpr ----------
extern "C" __global__ __launch_bounds__(128)
void k_prop(const float* __restrict__ hid, const uint2* __restrict__ cs,
            u16* __restrict__ xpr) {
    __shared__ float xl[NPS * 128];          // hop1 result (20 KB)
    __shared__ uint2 em[NENT];               // packed entries (800 B)

    int tid = threadIdx.x;
    int b   = blockIdx.x >> 2;
    int c0  = (blockIdx.x & 3) * 128;
    size_t nb = (size_t)b * NPS;

    if (tid < NENT) em[tid] = cs[(size_t)b * 128 + tid];
    __syncthreads();

    const float* __restrict__ xcol = hid + nb * DIM + c0 + tid;

    // ---- hop 1: gather from global (L2), accumulate, last-write-wins to xl ----
    {
        float a = 0.f; int prev = -1;
#pragma unroll 4
        for (int p = 0; p < NENT; p++) {
            uint2 e = em[p];
            int d = (e.x >> 8) & 0xff, s = e.x & 0xff;
            float nm = __uint_as_float(e.y);
            float xv = xcol[(size_t)s * DIM];
            a = (d == prev ? a : 0.f) + nm * xv;
            xl[d * 128 + tid] = a;           // unconditional; final write is full sum
            prev = d;
        }
    }

    // ---- hop 2: gather from xl (same-thread columns), write bf16 xpr ----
    {
        float a = 0.f; int prev = -1;
#pragma unroll 4
        for (int p = 0; p < NENT; p++) {
            uint2 e = em[p];
            int d = (e.x >> 8) & 0xff, s = e.x & 0xff;
            float nm = __uint_as_float(e.y);
            float xv = xl[s * 128 + tid];
            a = (d == prev ? a : 0.f) + nm * xv;
            prev = d;
            if (e.x & 0x10000u)
                xpr[(nb + d) * DIM + c0 + tid] = f2bf(a);
        }
    }
}

// ---------- GEMM1: C[N,512] = A[N,512] @ Wg + bg (A,BT,C bf16; bias fp32) --------
#define GEMM_NBLK ((NNODES / 128) * (DIM / 128))   // 5120, % 8 == 0
extern "C" __global__ __launch_bounds__(256)
void k_gemm(const u16* __restrict__ A, const u16* __restrict__ BT,
            const float* __restrict__ bias, u16* __restrict__ C) {
    __shared__ __align__(16) u16 As[128 * 32];
    __shared__ __align__(16) u16 Bs[128 * 32];
    int tid  = threadIdx.x, lane = tid & 63, w = tid >> 6;
    int id   = blockIdx.x;
    int swz  = (id & 7) * (GEMM_NBLK / 8) + (id >> 3);
    int m0   = (swz >> 2) * 128, n0 = (swz & 3) * 128;
    int wm   = (w >> 1) * 64,    wn = (w & 1) * 64;
    int fr   = lane & 15,        kq = (lane >> 4) * 8;
    int lr   = lane >> 2;              // staging: row within 16-row chunk
    int lk   = (lane & 3) * 8;         // staging: k offset (u16 units)
    f32x4 acc[4][4] = {};

    for (int kt = 0; kt < 16; kt++) {
        __syncthreads();
        int k0 = kt * 32;
#pragma unroll
        for (int q = 0; q < 2; q++) {
            int r0 = (w * 2 + q) * 16;
            GLOAD_LDS16(A  + (size_t)(m0 + r0 + lr) * DIM + k0 + lk, As + r0 * 32);
            GLOAD_LDS16(BT + (size_t)(n0 + r0 + lr) * DIM + k0 + lk, Bs + r0 * 32);
        }
        __syncthreads();
        bf16x8 av[4], bv[4];
#pragma unroll
        for (int f = 0; f < 4; f++)
            av[f] = *(const bf16x8*)&As[(wm + f * 16 + fr) * 32 + kq];
#pragma unroll
        for (int f = 0; f < 4; f++)
            bv[f] = *(const bf16x8*)&Bs[(wn + f * 16 + fr) * 32 + kq];
#pragma unroll
        for (int fm = 0; fm < 4; fm++)
#pragma unroll
            for (int fn = 0; fn < 4; fn++)
                acc[fm][fn] = __builtin_amdgcn_mfma_f32_16x16x32_bf16(
                    av[fm], bv[fn], acc[fm][fn], 0, 0, 0);
    }

    float bs[4];
#pragma unroll
    for (int fn = 0; fn < 4; fn++) bs[fn] = bias[n0 + wn + fn * 16 + fr];
#pragma unroll
    for (int fm = 0; fm < 4; fm++) {
        int mb = m0 + wm + fm * 16 + (lane >> 4) * 4;
#pragma unroll
        for (int fn = 0; fn < 4; fn++) {
            int col = n0 + wn + fn * 16 + fr;
#pragma unroll
            for (int r = 0; r < 4; r++)
                C[(size_t)(mb + r) * DIM + col] = f2bf(acc[fm][fn][r] + bs[fn]);
        }
    }
}

// ---------- A2 = xg @ W2  [N,64] bf16, dense streaming MFMA, no LDS ----------
// block: 256 rows (4 waves x 64 rows), full K=512, 64 output cols.
extern "C" __global__ __launch_bounds__(256)
void k_a2(const u16* __restrict__ xg, const u16* __restrict__ W2T,
          u16* __restrict__ A2) {
    int tid = threadIdx.x, lane = tid & 63, w = tid >> 6;
    int m0  = blockIdx.x * 256 + w * 64;
    int fr  = lane & 15, kq = (lane >> 4) * 8;
    f32x4 acc[4][4] = {};

    for (int kt = 0; kt < 16; kt++) {
        bf16x8 bv[4];
#pragma unroll
        for (int fn = 0; fn < 4; fn++)
            bv[fn] = *(const bf16x8*)&W2T[(size_t)(fn * 16 + fr) * DIM + kt * 32 + kq];
#pragma unroll
        for (int fm = 0; fm < 4; fm++) {
            bf16x8 av = *(const bf16x8*)&xg[(size_t)(m0 + fm * 16 + fr) * DIM + kt * 32 + kq];
#pragma unroll
            for (int fn = 0; fn < 4; fn++)
                acc[fm][fn] = __builtin_amdgcn_mfma_f32_16x16x32_bf16(
                    av, bv[fn], acc[fm][fn], 0, 0, 0);
        }
    }
#pragma unroll
    for (int fm = 0; fm < 4; fm++) {
        int mb = m0 + fm * 16 + (lane >> 4) * 4;
#pragma unroll
        for (int fn = 0; fn < 4; fn++) {
            int col = fn * 16 + fr;
#pragma unroll
            for (int r = 0; r < 4; r++)
                A2[(size_t)(mb + r) * HID + col] = f2bf(acc[fm][fn][r]);
        }
    }
}

// ---------- q1[b] = v_n[b] @ W1 + b1 + b2  [B,64] fp32 ----------
// block: 64 sessions, gather v_n rows to LDS, MFMA 16x16x32.
extern "C" __global__ __launch_bounds__(256)
void k_q1(const u16* __restrict__ xg, const u16* __restrict__ W1T,
          const float* __restrict__ b1, const float* __restrict__ b2,
          const int* __restrict__ sidx, float* __restrict__ q1g) {
    __shared__ __align__(16) u16 vs[64 * 520];
    int tid = threadIdx.x, lane = tid & 63, w = tid >> 6;
    int b0  = blockIdx.x * 64;

    for (int t = w; t < 64; t += 4) {
        int brow = b0 + t;
        size_t node = (size_t)brow * NPS + sidx[brow * SPS + SPS - 1];
        GLOAD_LDS16(xg + node * DIM + lane * 8, vs + t * 520);
    }
    __syncthreads();

    int fr = lane & 15, kq = (lane >> 4) * 8;
    f32x4 acc[4] = {};
    for (int kt = 0; kt < 16; kt++) {
        bf16x8 av = *(const bf16x8*)&vs[(w * 16 + fr) * 520 + kt * 32 + kq];
#pragma unroll
        for (int fn = 0; fn < 4; fn++) {
            bf16x8 bv = *(const bf16x8*)&W1T[(size_t)(fn * 16 + fr) * DIM + kt * 32 + kq];
            acc[fn] = __builtin_amdgcn_mfma_f32_16x16x32_bf16(av, bv, acc[fn], 0, 0, 0);
        }
    }
#pragma unroll
    for (int fn = 0; fn < 4; fn++) {
        int col = fn * 16 + fr;
        float bb = b1[col] + b2[col];
#pragma unroll
        for (int r = 0; r < 4; r++) {
            int brow = b0 + w * 16 + (lane >> 4) * 4 + r;
            q1g[(size_t)brow * HID + col] = acc[fn][r] + bb;
        }
    }
}

// ---------- lite attention pooling, one block per session (no big LDS) ----------
extern "C" __global__ __launch_bounds__(256)
void k_attn(const u16* __restrict__ xg, const u16* __restrict__ A2,
            const float* __restrict__ q1g, const float* __restrict__ Wq,
            const float* __restrict__ bq, const u16* __restrict__ W3T,
            const float* __restrict__ b3, const int* __restrict__ sidx,
            float* __restrict__ out) {
    __shared__ __align__(16) u16 a2s[SPS * HID];   // 6.4 KB
    __shared__ float q1s[64], wqs[64], alphas[64], sgs[512], part[256];
    __shared__ int   nodes[64];
    int tid = threadIdx.x, lane = tid & 63, w = tid >> 6;
    int b = blockIdx.x, sb = b * SPS;
    int nb = b * NPS;

    if (tid < SPS) nodes[tid] = nb + sidx[sb + tid];
    if (tid < 64) { q1s[tid] = q1g[(size_t)b * HID + tid]; wqs[tid] = Wq[tid]; }
    __syncthreads();

    // stage a2 token rows: 50 x 64 bf16 = 1600 u32
    {
        const u32* A2u = (const u32*)A2;
        u32* a2u = (u32*)a2s;
        for (int i = tid; i < SPS * (HID / 2); i += 256) {
            int r = i >> 5, c = i & 31;
            a2u[i] = A2u[(size_t)nodes[r] * (HID / 2) + c];
        }
    }
    __syncthreads();

    // alphas: wave w handles tokens w, w+4, ...
    float bqf = bq[0];
    for (int t = w; t < SPS; t += 4) {
        float x = bf2f(a2s[t * HID + lane]) + q1s[lane];
        float sg = 1.0f / (1.0f + __expf(-x));
        float s = sg * wqs[lane];
        s += __shfl_xor(s, 1);  s += __shfl_xor(s, 2);  s += __shfl_xor(s, 4);
        s += __shfl_xor(s, 8);  s += __shfl_xor(s, 16); s += __shfl_xor(s, 32);
        if (lane == 0) alphas[t] = s + bqf;
    }
    __syncthreads();

    // s_g: thread owns u32 column tid (2 bf16 cols); gather rows from xg (L3-hot)
    {
        const u32* xgu = (const u32*)xg;
        float a0 = 0.f, a1 = 0.f;
#pragma unroll 10
        for (int t = 0; t < SPS; t++) {
            float al = alphas[t];
            u32 xv = xgu[(size_t)nodes[t] * (DIM / 2) + tid];
            a0 += al * bf2f(xv & 0xffffu);
            a1 += al * bf2f(xv >> 16);
        }
        sgs[2 * tid] = a0; sgs[2 * tid + 1] = a1;
    }
    __syncthreads();

    // h_s = [v_n, s_g] @ W3 + b3  (W3T bf16 [64][1024]); wave w covers k 256w..+256
    {
        float s = 0.f;
        const u16* wp = W3T + (size_t)lane * 1024 + 256 * w;
        if (w < 2) {
            const u16* vp = xg + (size_t)nodes[SPS - 1] * DIM + 256 * w;
            for (int kk = 0; kk < 256; kk += 8) {
                uint4 vv = *(const uint4*)(vp + kk);
                uint4 ww = *(const uint4*)(wp + kk);
                s += bf2f(vv.x & 0xffffu) * bf2f(ww.x & 0xffffu)
                   + bf2f(vv.x >> 16)     * bf2f(ww.x >> 16)
                   + bf2f(vv.y & 0xffffu) * bf2f(ww.y & 0xffffu)
                   + bf2f(vv.y >> 16)     * bf2f(ww.y >> 16)
                   + bf2f(vv.z & 0xffffu) * bf2f(ww.z & 0xffffu)
                   + bf2f(vv.z >> 16)     * bf2f(ww.z >> 16)
                   + bf2f(vv.w & 0xffffu) * bf2f(ww.w & 0xffffu)
                   + bf2f(vv.w >> 16)     * bf2f(ww.w >> 16);
            }
        } else {
            const float* sp = sgs + 256 * (w - 2);
            for (int kk = 0; kk < 256; kk += 8) {
                uint4 ww = *(const uint4*)(wp + kk);
                s += sp[kk + 0] * bf2f(ww.x & 0xffffu) + sp[kk + 1] * bf2f(ww.x >> 16)
                   + sp[kk + 2] * bf2f(ww.y & 0xffffu) + sp[kk + 3] * bf2f(ww.y >> 16)
                   + sp[kk + 4] * bf2f(ww.z & 0xffffu) + sp[kk + 5] * bf2f(ww.z >> 16)
                   + sp[kk + 6] * bf2f(ww.w & 0xffffu) + sp[kk + 7] * bf2f(ww.w >> 16);
            }
        }
        part[w * 64 + lane] = s;
    }
    __syncthreads();
    if (tid < 64) {
        out[b * HID + tid] = part[tid] + part[64 + tid] + part[128 + tid]
                           + part[192 + tid] + b3[tid];
    }
}

extern "C" void kernel_launch(void* const* d_in, const int* in_sizes, int n_in,
                              void* d_out, int out_size, void* d_ws, size_t ws_size,
                              hipStream_t stream) {
    const float* hidden = (const float*)d_in[0];
    const float* Wg     = (const float*)d_in[1];
    const float* bg     = (const float*)d_in[2];
    const float* W1     = (const float*)d_in[3];
    const float* b1     = (const float*)d_in[4];
    const float* W2     = (const float*)d_in[5];
    const float* b2     = (const float*)d_in[6];
    const float* Wq     = (const float*)d_in[7];
    const float* bq     = (const float*)d_in[8];
    const float* W3     = (const float*)d_in[9];
    const float* b3     = (const float*)d_in[10];
    const int*   eidx   = (const int*)d_in[11];
    const int*   sidx   = (const int*)d_in[13];
    int Etot = in_sizes[11] / 2;

    char* ws = (char*)d_ws;
    u16* xpr = (u16*)ws;                                   // N*D bf16 (160 MB)
    u16* xg  = (u16*)(ws + (size_t)NNODES * DIM * 2);      // N*D bf16 (160 MB)
    u16* WgT = (u16*)(ws + (size_t)NNODES * DIM * 4);      // 512x512 bf16
    u16* W2T = WgT + DIM * DIM;                            // 64x512  bf16
    u16* W1T = W2T + DIM * HID;                            // 64x512  bf16
    u16* W3T = W1T + DIM * HID;                            // 64x1024 bf16
    uint2* cs = (uint2*)(W3T + 2 * DIM * HID);             // 4096x128 uint2 (4 MB)
    // A2 / q1 reuse the dead xpr region (xpr unused after k_gemm)
    u16*   A2  = xpr;                                      // N*64 bf16 (20 MB)
    float* q1g = (float*)(ws + (size_t)NNODES * HID * 2);  // B*64 fp32 (1 MB)

    k_convT<<<dim3((DIM * DIM + 255) / 256), 256, 0, stream>>>(Wg, WgT, DIM, DIM);
    k_convT<<<dim3((DIM * HID + 255) / 256), 256, 0, stream>>>(W2, W2T, DIM, HID);
    k_convT<<<dim3((DIM * HID + 255) / 256), 256, 0, stream>>>(W1, W1T, DIM, HID);
    k_convT<<<dim3((2 * DIM * HID + 255) / 256), 256, 0, stream>>>(W3, W3T, 2 * DIM, HID);
    k_csr<<<dim3(B_SESS), 128, 0, stream>>>(eidx, Etot, cs);
    k_prop<<<dim3(B_SESS * 4), 128, 0, stream>>>(hidden, cs, xpr);
    k_gemm<<<dim3(GEMM_NBLK), 256, 0, stream>>>(xpr, WgT, bg, xg);
    k_a2<<<dim3(NNODES / 256), 256, 0, stream>>>(xg, W2T, A2);
    k_q1<<<dim3(B_SESS / 64), 256, 0, stream>>>(xg, W1T, b1, b2, sidx, q1g);
    k_attn<<<dim3(B_SESS), 256, 0, stream>>>(xg, A2, q1g, Wq, bq, W3T, b3,
                                             sidx, (float*)d_out);
}

// Round 4
// 969.194 us; speedup vs baseline: 1.5212x; 1.0065x over previous
//
#include <hip/hip_runtime.h>

typedef unsigned int  u32;
typedef unsigned short u16;

#define B_SESS 4096
#define NPS    40          // nodes / session
#define SPS    50          // seq tokens / session
#define EPS    60          // edges / session
#define DIM    512
#define HID    64
#define NNODES (B_SESS * NPS)
#define CSS    1600        // cs entry stride / session (worst-case nnz of P^2)

// ---------- bf16 helpers (RNE) ----------
__device__ __forceinline__ float bf2f(u32 b) { return __uint_as_float(b << 16); }
__device__ __forceinline__ u16  f2bf(float f) {
    u32 u = __float_as_uint(f);
    return (u16)((u + 0x7fffu + ((u >> 16) & 1u)) >> 16);
}
__device__ __forceinline__ u32 pack2(float a, float b) {
    return (u32)f2bf(a) | ((u32)f2bf(b) << 16);
}

typedef __bf16 bf16x8 __attribute__((ext_vector_type(8)));
typedef float  f32x4  __attribute__((ext_vector_type(4)));

typedef const __attribute__((address_space(1))) u32 gu32;
typedef       __attribute__((address_space(3))) u32 lu32;
#define GLOAD_LDS16(gp, lp) \
    __builtin_amdgcn_global_load_lds((gu32*)(gp), (lu32*)(lp), 16, 0, 0)

// ---------- transpose + fp32->bf16 convert: dst[c*R + r] = bf16(src[r*C + c]) ----
extern "C" __global__ void k_convT(const float* __restrict__ src,
                                   u16* __restrict__ dst, int R, int C) {
    int i = blockIdx.x * 256 + threadIdx.x;
    if (i < R * C) {
        int r = i / C, c = i % C;
        dst[c * R + r] = f2bf(src[i]);
    }
}

// ---------- build sparse P^2 per session (P = D^-1/2 (A+I) D^-1/2) ----------
// Emits dst-sorted entries: e.x = (lastOfDst << 16) | (dst << 8) | src,
// e.y = bits(P2[dst][src]);  cnt[b] = number of entries.
extern "C" __global__ __launch_bounds__(128)
void k_csr(const int* __restrict__ eidx, int Etot,
           uint2* __restrict__ cs, int* __restrict__ cnt) {
    __shared__ float P [NPS][NPS];           // 6.4 KB
    __shared__ float P2[NPS][NPS];           // 6.4 KB
    __shared__ int   degc[NPS];
    __shared__ float dinv[NPS];
    __shared__ int   se[EPS], de[EPS];
    __shared__ int   rc[NPS], offs[NPS + 1];

    int tid = threadIdx.x;
    int b   = blockIdx.x;
    int nb  = b * NPS;

    if (tid < EPS) {
        se[tid] = eidx[b * EPS + tid] - nb;
        de[tid] = eidx[Etot + b * EPS + tid] - nb;
    }
    if (tid < NPS) degc[tid] = 1;            // self loop
    for (int i = tid; i < NPS * NPS; i += 128) (&P[0][0])[i] = 0.f;
    __syncthreads();
    if (tid < EPS) atomicAdd(&degc[de[tid]], 1);
    __syncthreads();
    if (tid < NPS) dinv[tid] = rsqrtf((float)degc[tid]);
    __syncthreads();
    if (tid < NPS) atomicAdd(&P[tid][tid], dinv[tid] * dinv[tid]);
    if (tid < EPS) {
        int s = se[tid], d = de[tid];
        atomicAdd(&P[d][s], dinv[s] * dinv[d]);
    }
    __syncthreads();

    // P2 = P @ P  (thread computes a 1x4 chunk; LDS b128 reads on the k-row)
    for (int i = tid; i < NPS * (NPS / 4); i += 128) {
        int d = i / (NPS / 4), q = (i % (NPS / 4)) * 4;
        float4 acc = make_float4(0.f, 0.f, 0.f, 0.f);
#pragma unroll 8
        for (int k = 0; k < NPS; k++) {
            float  pk = P[d][k];
            float4 pv = *(const float4*)&P[k][q];
            acc.x += pk * pv.x; acc.y += pk * pv.y;
            acc.z += pk * pv.z; acc.w += pk * pv.w;
        }
        *(float4*)&P2[d][q] = acc;
    }
    __syncthreads();

    if (tid < NPS) {                         // row nnz (all entries >= 0)
        int c = 0;
        for (int s = 0; s < NPS; s++) c += (P2[tid][s] > 0.f);
        rc[tid] = c;
    }
    __syncthreads();
    if (tid == 0) {
        int s = 0;
        for (int i = 0; i < NPS; i++) { offs[i] = s; s += rc[i]; }
        offs[NPS] = s;
        cnt[b] = s;
    }
    __syncthreads();
    if (tid < NPS) {
        int d = tid, o = offs[d], last = offs[d] + rc[d] - 1;
        for (int s = 0; s < NPS; s++) {
            float v = P2[d][s];
            if (v > 0.f) {
                u32 x = (u32)(d << 8) | (u32)s | ((o == last) ? 0x10000u : 0u);
                cs[(size_t)b * CSS + o] = make_uint2(x, __float_as_uint(v));
                o++;
            }
        }
    }
}

// ---------- SGConv propagation: xpr = P^2 @ hidden, fp32 -> bf16 ----------
// one block per session, zero LDS; thread owns 4 columns (float4 loads).
// Entry stream is wave-uniform (scalar loads); XCD swizzle keeps a session's
// 80 KB working set on one XCD's L2.
extern "C" __global__ __launch_bounds__(128)
void k_prop(const float* __restrict__ hid, const uint2* __restrict__ cs,
            const int* __restrict__ cnt, u16* __restrict__ xpr) {
    int tid = threadIdx.x;
    int b   = (blockIdx.x & 7) * (B_SESS / 8) + (blockIdx.x >> 3);
    int n   = cnt[b];
    const uint2*  em = cs + (size_t)b * CSS;
    const float4* xr = (const float4*)(hid + (size_t)b * NPS * DIM) + tid;
    u16*          xo = xpr + (size_t)b * NPS * DIM + tid * 4;

    float a0 = 0.f, a1 = 0.f, a2 = 0.f, a3 = 0.f;
#pragma unroll 8
    for (int p = 0; p < n; p++) {
        uint2 e = em[p];
        float nm = __uint_as_float(e.y);
        float4 v = xr[(size_t)(e.x & 0xffu) * (DIM / 4)];
        a0 += nm * v.x; a1 += nm * v.y; a2 += nm * v.z; a3 += nm * v.w;
        if (e.x & 0x10000u) {
            int d = (e.x >> 8) & 0xffu;
            *(uint2*)(xo + (size_t)d * DIM) = make_uint2(pack2(a0, a1), pack2(a2, a3));
            a0 = a1 = a2 = a3 = 0.f;
        }
    }
}

// ---------- GEMM1: C[N,512] = A[N,512] @ Wg + bg (A,BT,C bf16; bias fp32) --------
#define GEMM_NBLK ((NNODES / 128) * (DIM / 128))   // 5120, % 8 == 0
extern "C" __global__ __launch_bounds__(256)
void k_gemm(const u16* __restrict__ A, const u16* __restrict__ BT,
            const float* __restrict__ bias, u16* __restrict__ C) {
    __shared__ __align__(16) u16 As[128 * 32];
    __shared__ __align__(16) u16 Bs[128 * 32];
    int tid  = threadIdx.x, lane = tid & 63, w = tid >> 6;
    int id   = blockIdx.x;
    int swz  = (id & 7) * (GEMM_NBLK / 8) + (id >> 3);
    int m0   = (swz >> 2) * 128, n0 = (swz & 3) * 128;
    int wm   = (w >> 1) * 64,    wn = (w & 1) * 64;
    int fr   = lane & 15,        kq = (lane >> 4) * 8;
    int lr   = lane >> 2;              // staging: row within 16-row chunk
    int lk   = (lane & 3) * 8;         // staging: k offset (u16 units)
    f32x4 acc[4][4] = {};

    for (int kt = 0; kt < 16; kt++) {
        __syncthreads();
        int k0 = kt * 32;
#pragma unroll
        for (int q = 0; q < 2; q++) {
            int r0 = (w * 2 + q) * 16;
            GLOAD_LDS16(A  + (size_t)(m0 + r0 + lr) * DIM + k0 + lk, As + r0 * 32);
            GLOAD_LDS16(BT + (size_t)(n0 + r0 + lr) * DIM + k0 + lk, Bs + r0 * 32);
        }
        __syncthreads();
        bf16x8 av[4], bv[4];
#pragma unroll
        for (int f = 0; f < 4; f++)
            av[f] = *(const bf16x8*)&As[(wm + f * 16 + fr) * 32 + kq];
#pragma unroll
        for (int f = 0; f < 4; f++)
            bv[f] = *(const bf16x8*)&Bs[(wn + f * 16 + fr) * 32 + kq];
#pragma unroll
        for (int fm = 0; fm < 4; fm++)
#pragma unroll
            for (int fn = 0; fn < 4; fn++)
                acc[fm][fn] = __builtin_amdgcn_mfma_f32_16x16x32_bf16(
                    av[fm], bv[fn], acc[fm][fn], 0, 0, 0);
    }

    float bs[4];
#pragma unroll
    for (int fn = 0; fn < 4; fn++) bs[fn] = bias[n0 + wn + fn * 16 + fr];
#pragma unroll
    for (int fm = 0; fm < 4; fm++) {
        int mb = m0 + wm + fm * 16 + (lane >> 4) * 4;
#pragma unroll
        for (int fn = 0; fn < 4; fn++) {
            int col = n0 + wn + fn * 16 + fr;
#pragma unroll
            for (int r = 0; r < 4; r++)
                C[(size_t)(mb + r) * DIM + col] = f2bf(acc[fm][fn][r] + bs[fn]);
        }
    }
}

// ---------- A2 = xg @ W2  [N,64] bf16, dense streaming MFMA, no LDS ----------
extern "C" __global__ __launch_bounds__(256)
void k_a2(const u16* __restrict__ xg, const u16* __restrict__ W2T,
          u16* __restrict__ A2) {
    int tid = threadIdx.x, lane = tid & 63, w = tid >> 6;
    int m0  = blockIdx.x * 256 + w * 64;
    int fr  = lane & 15, kq = (lane >> 4) * 8;
    f32x4 acc[4][4] = {};

    for (int kt = 0; kt < 16; kt++) {
        bf16x8 bv[4];
#pragma unroll
        for (int fn = 0; fn < 4; fn++)
            bv[fn] = *(const bf16x8*)&W2T[(size_t)(fn * 16 + fr) * DIM + kt * 32 + kq];
#pragma unroll
        for (int fm = 0; fm < 4; fm++) {
            bf16x8 av = *(const bf16x8*)&xg[(size_t)(m0 + fm * 16 + fr) * DIM + kt * 32 + kq];
#pragma unroll
            for (int fn = 0; fn < 4; fn++)
                acc[fm][fn] = __builtin_amdgcn_mfma_f32_16x16x32_bf16(
                    av, bv[fn], acc[fm][fn], 0, 0, 0);
        }
    }
#pragma unroll
    for (int fm = 0; fm < 4; fm++) {
        int mb = m0 + fm * 16 + (lane >> 4) * 4;
#pragma unroll
        for (int fn = 0; fn < 4; fn++) {
            int col = fn * 16 + fr;
#pragma unroll
            for (int r = 0; r < 4; r++)
                A2[(size_t)(mb + r) * HID + col] = f2bf(acc[fm][fn][r]);
        }
    }
}

// ---------- q1[b] = v_n[b] @ W1 + b1 + b2  [B,64] fp32 ----------
extern "C" __global__ __launch_bounds__(256)
void k_q1(const u16* __restrict__ xg, const u16* __restrict__ W1T,
          const float* __restrict__ b1, const float* __restrict__ b2,
          const int* __restrict__ sidx, float* __restrict__ q1g) {
    __shared__ __align__(16) u16 vs[64 * 520];
    int tid = threadIdx.x, lane = tid & 63, w = tid >> 6;
    int b0  = blockIdx.x * 64;

    for (int t = w; t < 64; t += 4) {
        int brow = b0 + t;
        size_t node = (size_t)brow * NPS + sidx[brow * SPS + SPS - 1];
        GLOAD_LDS16(xg + node * DIM + lane * 8, vs + t * 520);
    }
    __syncthreads();

    int fr = lane & 15, kq = (lane >> 4) * 8;
    f32x4 acc[4] = {};
    for (int kt = 0; kt < 16; kt++) {
        bf16x8 av = *(const bf16x8*)&vs[(w * 16 + fr) * 520 + kt * 32 + kq];
#pragma unroll
        for (int fn = 0; fn < 4; fn++) {
            bf16x8 bv = *(const bf16x8*)&W1T[(size_t)(fn * 16 + fr) * DIM + kt * 32 + kq];
            acc[fn] = __builtin_amdgcn_mfma_f32_16x16x32_bf16(av, bv, acc[fn], 0, 0, 0);
        }
    }
#pragma unroll
    for (int fn = 0; fn < 4; fn++) {
        int col = fn * 16 + fr;
        float bb = b1[col] + b2[col];
#pragma unroll
        for (int r = 0; r < 4; r++) {
            int brow = b0 + w * 16 + (lane >> 4) * 4 + r;
            q1g[(size_t)brow * HID + col] = acc[fn][r] + bb;
        }
    }
}

// ---------- lite attention pooling, one block per session (no big LDS) ----------
extern "C" __global__ __launch_bounds__(256)
void k_attn(const u16* __restrict__ xg, const u16* __restrict__ A2,
            const float* __restrict__ q1g, const float* __restrict__ Wq,
            const float* __restrict__ bq, const u16* __restrict__ W3T,
            const float* __restrict__ b3, const int* __restrict__ sidx,
            float* __restrict__ out) {
    __shared__ __align__(16) u16 a2s[SPS * HID];   // 6.4 KB
    __shared__ float q1s[64], wqs[64], alphas[64], sgs[512], part[256];
    __shared__ int   nodes[64];
    int tid = threadIdx.x, lane = tid & 63, w = tid >> 6;
    int b = blockIdx.x, sb = b * SPS;
    int nb = b * NPS;

    if (tid < SPS) nodes[tid] = nb + sidx[sb + tid];
    if (tid < 64) { q1s[tid] = q1g[(size_t)b * HID + tid]; wqs[tid] = Wq[tid]; }
    __syncthreads();

    // stage a2 token rows: 50 x 64 bf16 = 1600 u32
    {
        const u32* A2u = (const u32*)A2;
        u32* a2u = (u32*)a2s;
        for (int i = tid; i < SPS * (HID / 2); i += 256) {
            int r = i >> 5, c = i & 31;
            a2u[i] = A2u[(size_t)nodes[r] * (HID / 2) + c];
        }
    }
    __syncthreads();

    // alphas: wave w handles tokens w, w+4, ...
    float bqf = bq[0];
    for (int t = w; t < SPS; t += 4) {
        float x = bf2f(a2s[t * HID + lane]) + q1s[lane];
        float sg = 1.0f / (1.0f + __expf(-x));
        float s = sg * wqs[lane];
        s += __shfl_xor(s, 1);  s += __shfl_xor(s, 2);  s += __shfl_xor(s, 4);
        s += __shfl_xor(s, 8);  s += __shfl_xor(s, 16); s += __shfl_xor(s, 32);
        if (lane == 0) alphas[t] = s + bqf;
    }
    __syncthreads();

    // s_g: thread owns u32 column tid (2 bf16 cols); gather rows from xg (L3-hot)
    {
        const u32* xgu = (const u32*)xg;
        float a0 = 0.f, a1 = 0.f;
#pragma unroll 10
        for (int t = 0; t < SPS; t++) {
            float al = alphas[t];
            u32 xv = xgu[(size_t)nodes[t] * (DIM / 2) + tid];
            a0 += al * bf2f(xv & 0xffffu);
            a1 += al * bf2f(xv >> 16);
        }
        sgs[2 * tid] = a0; sgs[2 * tid + 1] = a1;
    }
    __syncthreads();

    // h_s = [v_n, s_g] @ W3 + b3  (W3T bf16 [64][1024]); wave w covers k 256w..+256
    {
        float s = 0.f;
        const u16* wp = W3T + (size_t)lane * 1024 + 256 * w;
        if (w < 2) {
            const u16* vp = xg + (size_t)nodes[SPS - 1] * DIM + 256 * w;
            for (int kk = 0; kk < 256; kk += 8) {
                uint4 vv = *(const uint4*)(vp + kk);
                uint4 ww = *(const uint4*)(wp + kk);
                s += bf2f(vv.x & 0xffffu) * bf2f(ww.x & 0xffffu)
                   + bf2f(vv.x >> 16)     * bf2f(ww.x >> 16)
                   + bf2f(vv.y & 0xffffu) * bf2f(ww.y & 0xffffu)
                   + bf2f(vv.y >> 16)     * bf2f(ww.y >> 16)
                   + bf2f(vv.z & 0xffffu) * bf2f(ww.z & 0xffffu)
                   + bf2f(vv.z >> 16)     * bf2f(ww.z >> 16)
                   + bf2f(vv.w & 0xffffu) * bf2f(ww.w & 0xffffu)
                   + bf2f(vv.w >> 16)     * bf2f(ww.w >> 16);
            }
        } else {
            const float* sp = sgs + 256 * (w - 2);
            for (int kk = 0; kk < 256; kk += 8) {
                uint4 ww = *(const uint4*)(wp + kk);
                s += sp[kk + 0] * bf2f(ww.x & 0xffffu) + sp[kk + 1] * bf2f(ww.x >> 16)
                   + sp[kk + 2] * bf2f(ww.y & 0xffffu) + sp[kk + 3] * bf2f(ww.y >> 16)
                   + sp[kk + 4] * bf2f(ww.z & 0xffffu) + sp[kk + 5] * bf2f(ww.z >> 16)
                   + sp[kk + 6] * bf2f(ww.w & 0xffffu) + sp[kk + 7] * bf2f(ww.w >> 16);
            }
        }
        part[w * 64 + lane] = s;
    }
    __syncthreads();
    if (tid < 64) {
        out[b * HID + tid] = part[tid] + part[64 + tid] + part[128 + tid]
                           + part[192 + tid] + b3[tid];
    }
}

extern "C" void kernel_launch(void* const* d_in, const int* in_sizes, int n_in,
                              void* d_out, int out_size, void* d_ws, size_t ws_size,
                              hipStream_t stream) {
    const float* hidden = (const float*)d_in[0];
    const float* Wg     = (const float*)d_in[1];
    const float* bg     = (const float*)d_in[2];
    const float* W1     = (const float*)d_in[3];
    const float* b1     = (const float*)d_in[4];
    const float* W2     = (const float*)d_in[5];
    const float* b2     = (const float*)d_in[6];
    const float* Wq     = (const float*)d_in[7];
    const float* bq     = (const float*)d_in[8];
    const float* W3     = (const float*)d_in[9];
    const float* b3     = (const float*)d_in[10];
    const int*   eidx   = (const int*)d_in[11];
    const int*   sidx   = (const int*)d_in[13];
    int Etot = in_sizes[11] / 2;

    char* ws = (char*)d_ws;
    u16* xpr = (u16*)ws;                                   // N*D bf16 (160 MB)
    u16* xg  = (u16*)(ws + (size_t)NNODES * DIM * 2);      // N*D bf16 (160 MB)
    u16* WgT = (u16*)(ws + (size_t)NNODES * DIM * 4);      // 512x512 bf16
    u16* W2T = WgT + DIM * DIM;                            // 64x512  bf16
    u16* W1T = W2T + DIM * HID;                            // 64x512  bf16
    u16* W3T = W1T + DIM * HID;                            // 64x1024 bf16
    int* cnt = (int*)(W3T + 2 * DIM * HID);                // B ints (16 KB)
    // cs aliases the xg region: written by k_csr, read by k_prop, dead before
    // k_gemm writes xg (same-stream kernels serialize).
    uint2* cs = (uint2*)xg;                                // 4096x1600 uint2 (52 MB)
    // A2 / q1 reuse the dead xpr region (xpr unused after k_gemm)
    u16*   A2  = xpr;                                      // N*64 bf16 (20 MB)
    float* q1g = (float*)(ws + (size_t)NNODES * HID * 2);  // B*64 fp32 (1 MB)

    k_convT<<<dim3((DIM * DIM + 255) / 256), 256, 0, stream>>>(Wg, WgT, DIM, DIM);
    k_convT<<<dim3((DIM * HID + 255) / 256), 256, 0, stream>>>(W2, W2T, DIM, HID);
    k_convT<<<dim3((DIM * HID + 255) / 256), 256, 0, stream>>>(W1, W1T, DIM, HID);
    k_convT<<<dim3((2 * DIM * HID + 255) / 256), 256, 0, stream>>>(W3, W3T, 2 * DIM, HID);
    k_csr<<<dim3(B_SESS), 128, 0, stream>>>(eidx, Etot, cs, cnt);
    k_prop<<<dim3(B_SESS * 8 / 8 * 8 == B_SESS ? B_SESS : B_SESS), 128, 0, stream>>>(hidden, cs, cnt, xpr);
    k_gemm<<<dim3(GEMM_NBLK), 256, 0, stream>>>(xpr, WgT, bg, xg);
    k_a2<<<dim3(NNODES / 256), 256, 0, stream>>>(xg, W2T, A2);
    k_q1<<<dim3(B_SESS / 64), 256, 0, stream>>>(xg, W1T, b1, b2, sidx, q1g);
    k_attn<<<dim3(B_SESS), 256, 0, stream>>>(xg, A2, q1g, Wq, bq, W3T, b3,
                                             sidx, (float*)d_out);
}